// Round 20
// baseline (91.567 us; speedup 1.0000x reference)
//
#include <hip/hip_runtime.h>

#define N_NODES 4096
#define C_CH    128
#define E_ELEM  10
#define NP      4736          // padded sorted-node space (64-aligned per element)
#define NB      16            // decode/scatter blocks (256 nodes each)
#define TT      219           // 9 deg1 + 45 deg2 + 165 deg3 monomials
#define PSTRIDE (TT * 4)      // 876 floats per (e,c): [t][m], m0=L0, m1..3=L1
#define MAXCHUNK 32
#define CHUNK_J  256          // j-slots per k_poly block (256 thr x 1 node)

// ws layout (bytes):
#define WS_CHE     256
#define WS_CHJ     512
#define WS_CHEND   768
#define WS_JLIST   1024        // int[4736]
#define WS_ELEM    20480       // int[4096]
#define WS_BCNT    36864       // int[160] per-block element counts
#define WS_S31     53248       // float[3465]
#define WS_S30     67136       // float[825]
#define WS_S21     70464       // float[405]
#define WS_S20     72128       // float[90]
#define WS_P       72704       // float[1280*876] = 4485120 B
#define WS_BOUT    4557824     // float[512*4736] = 9699328 B

// NOTE (R18): hipLaunchCooperativeKernel + grid.sync() DEADLOCKS under the
// harness's graph capture. Plain stream launches only.

__device__ __forceinline__ void t3_decode(int t, int& a, int& b, int& i) {
    int cnt = 0;
    for (int aa = 0; aa < 9; ++aa)
        for (int bb = aa; bb < 9; ++bb) {
            int len = 9 - bb;
            if (t < cnt + len) { a = aa; b = bb; i = bb + (t - cnt); return; }
            cnt += len;
        }
    a = b = i = 8;
}

__device__ __forceinline__ void t2_decode(int t, int& a, int& b) {
    int cnt = 0;
    for (int aa = 0; aa < 9; ++aa) {
        int len = 9 - aa;
        if (t < cnt + len) { a = aa; b = aa + (t - cnt); return; }
        cnt += len;
    }
    a = b = 8;
}

// Front: blocks 0-18 symmetrize U; blocks 19-34 decode elem AND produce
// per-block element counts bcnt[b][e].
__global__ __launch_bounds__(256) void k_front(
    const float* __restrict__ attrs, int* __restrict__ elem,
    int* __restrict__ bcnt,
    const float* __restrict__ U3_1, const float* __restrict__ U3_0,
    const float* __restrict__ U2_1, const float* __restrict__ U2_0,
    float* __restrict__ S31, float* __restrict__ S30,
    float* __restrict__ S21, float* __restrict__ S20) {
    int bid = blockIdx.x;
    int tid = threadIdx.x;
    if (bid >= 19) {
        __shared__ int h[E_ELEM];
        if (tid < E_ELEM) h[tid] = 0;
        __syncthreads();
        int b = bid - 19;
        int n = b * 256 + tid;                      // 16*256 = 4096 exact
        const float* a = attrs + n * E_ELEM;
        float best = a[0];
        int e = 0;
#pragma unroll
        for (int k = 1; k < E_ELEM; ++k) {
            float v = a[k];
            if (v > best) { best = v; e = k; }
        }
        elem[n] = e;
        atomicAdd(&h[e], 1);
        __syncthreads();
        if (tid < E_ELEM) bcnt[b * E_ELEM + tid] = h[tid];
        return;
    }
    int q = bid * 256 + tid;
    if (q < 3465) {                                 // S31 [m][t][p], p=7
        int m = q / 1155, r = q % 1155, t = r / 7, p = r % 7;
        int a, b, i;
        t3_decode(t, a, b, i);
#define U31(X, Y, Z) U3_1[((((m * 9 + (X)) * 9 + (Y)) * 9 + (Z)) * 7) + p]
        float s = U31(a, b, i);
        if (a == b && b == i) {}
        else if (a == b) s += U31(a, i, a) + U31(i, a, a);
        else if (b == i) s += U31(b, a, b) + U31(b, b, a);
        else s += U31(a, i, b) + U31(b, a, i) + U31(b, i, a) + U31(i, a, b) + U31(i, b, a);
#undef U31
        S31[q] = s;
        return;
    }
    q -= 3465;
    if (q < 825) {                                  // S30 [t][p], p=5
        int t = q / 5, p = q % 5;
        int a, b, i;
        t3_decode(t, a, b, i);
#define U30(X, Y, Z) U3_0[((((X) * 9 + (Y)) * 9 + (Z)) * 5) + p]
        float s = U30(a, b, i);
        if (a == b && b == i) {}
        else if (a == b) s += U30(a, i, a) + U30(i, a, a);
        else if (b == i) s += U30(b, a, b) + U30(b, b, a);
        else s += U30(a, i, b) + U30(b, a, i) + U30(b, i, a) + U30(i, a, b) + U30(i, b, a);
#undef U30
        S30[q] = s;
        return;
    }
    q -= 825;
    if (q < 405) {                                  // S21 [m][t][p], p=3
        int m = q / 135, r = q % 135, t = r / 3, p = r % 3;
        int a, b;
        t2_decode(t, a, b);
        float s = U2_1[(((m * 9 + a) * 9 + b) * 3) + p];
        if (a != b) s += U2_1[(((m * 9 + b) * 9 + a) * 3) + p];
        S21[q] = s;
        return;
    }
    q -= 405;
    if (q < 90) {                                   // S20 [t][p], p=2
        int t = q / 2, p = q % 2;
        int a, b;
        t2_decode(t, a, b);
        float s = U2_0[((a * 9 + b) * 2) + p];
        if (a != b) s += U2_0[((b * 9 + a) * 2) + p];
        S20[q] = s;
    }
}

// Redundant 160-int scan: every block computes the padded prefix itself.
__device__ __forceinline__ void scan_bcnt(const int* __restrict__ bcnt,
                                          int tid, int (&s_bc)[NB * E_ELEM],
                                          int (&s_cnt)[E_ELEM], int (&s_ps)[E_ELEM + 1]) {
    if (tid < NB * E_ELEM) s_bc[tid] = bcnt[tid];
    __syncthreads();
    if (tid < E_ELEM) {
        int c = 0;
#pragma unroll
        for (int b = 0; b < NB; ++b) c += s_bc[b * E_ELEM + tid];
        s_cnt[tid] = c;
    }
    __syncthreads();
    if (tid == 0) {
        int s = 0;
        for (int e = 0; e < E_ELEM; ++e) {
            s_ps[e] = s;
            s += ((s_cnt[e] + 63) >> 6) << 6;       // 64-align each range
        }
        s_ps[E_ELEM] = s;
    }
    __syncthreads();
}

// Sort+table+fold, all parallel (proven R15 shape).
__global__ __launch_bounds__(256) void k_sortfold(
    const int* __restrict__ elem, const int* __restrict__ bcnt,
    int* __restrict__ jlist,
    int* __restrict__ chE, int* __restrict__ chJ, int* __restrict__ chEnd,
    const float* __restrict__ S31, const float* __restrict__ S30,
    const float* __restrict__ S21, const float* __restrict__ S20,
    const float* __restrict__ U1_1, const float* __restrict__ U1_0,
    const float* __restrict__ W3_1, const float* __restrict__ W3_0,
    const float* __restrict__ W2_1, const float* __restrict__ W2_0,
    const float* __restrict__ W1_1, const float* __restrict__ W1_0,
    float* __restrict__ P) {
    const int bid = blockIdx.x;
    const int tid = threadIdx.x;
    if (bid < NB) {                                 // scatter blocks
        __shared__ int s_bc[NB * E_ELEM];
        __shared__ int s_cnt[E_ELEM];
        __shared__ int s_ps[E_ELEM + 1];
        __shared__ int cur[E_ELEM];
        scan_bcnt(bcnt, tid, s_bc, s_cnt, s_ps);
        if (tid < E_ELEM) {
            int off = s_ps[tid];
            for (int b = 0; b < bid; ++b) off += s_bc[b * E_ELEM + tid];
            cur[tid] = off;
        }
        __syncthreads();
        int n = bid * 256 + tid;
        int e = elem[n];
        int pos = atomicAdd(&cur[e], 1);
        jlist[pos] = n;
        return;
    }
    if (bid == NB) {                                // table + pad fill
        __shared__ int s_bc[NB * E_ELEM];
        __shared__ int s_cnt[E_ELEM];
        __shared__ int s_ps[E_ELEM + 1];
        scan_bcnt(bcnt, tid, s_bc, s_cnt, s_ps);
        if (tid == 0) {
            int ci = 0;
            for (int e = 0; e < E_ELEM; ++e) {
                int base = s_ps[e], pend = s_ps[e + 1];
                int end = base + s_cnt[e];
                for (int ofs = base; ofs < pend; ofs += CHUNK_J) {
                    chE[ci] = e;
                    chJ[ci] = ofs;
                    chEnd[ci] = end;
                    ++ci;
                }
            }
            for (; ci < MAXCHUNK; ++ci) chE[ci] = -1;
        }
        for (int j = tid; j < NP; j += 256) {
            bool pad = j >= s_ps[E_ELEM];
            if (!pad) {
#pragma unroll
                for (int e = 0; e < E_ELEM; ++e)
                    if (j >= s_ps[e] && j < s_ps[e + 1] && j >= s_ps[e] + s_cnt[e])
                        pad = true;
            }
            if (pad) jlist[j] = -1;
        }
        return;
    }
    // fold blocks: (e,c) = bid - 17
    int fb = bid - NB - 1;
    int e = fb >> 7;
    int c = fb & 127;
    float* Pout = P + (size_t)fb * PSTRIDE;
    for (int q = tid; q < PSTRIDE; q += 256) {
        int t = q >> 2, m = q & 3;
        float v;
        if (t < 9) {
            int a = t;
            v = (m == 0) ? U1_0[a] * W1_0[e * C_CH + c]
                         : U1_1[(m - 1) * 9 + a] * W1_1[e * C_CH + c];
        } else if (t < 54) {
            int t2 = t - 9;
            float s = 0.f;
            if (m == 0) {
#pragma unroll
                for (int p = 0; p < 2; ++p)
                    s = fmaf(S20[t2 * 2 + p], W2_0[(e * 2 + p) * C_CH + c], s);
            } else {
#pragma unroll
                for (int p = 0; p < 3; ++p)
                    s = fmaf(S21[((m - 1) * 45 + t2) * 3 + p], W2_1[(e * 3 + p) * C_CH + c], s);
            }
            v = s;
        } else {
            int t3 = t - 54;
            float s = 0.f;
            if (m == 0) {
#pragma unroll
                for (int p = 0; p < 5; ++p)
                    s = fmaf(S30[t3 * 5 + p], W3_0[(e * 5 + p) * C_CH + c], s);
            } else {
#pragma unroll
                for (int p = 0; p < 7; ++p)
                    s = fmaf(S31[((m - 1) * 165 + t3) * 7 + p], W3_1[(e * 7 + p) * C_CH + c], s);
            }
            v = s;
        }
        Pout[q] = v;
    }
}

// 219-monomial cubic — proven body: s_load coefficients, NN=1,
// sched_barrier(0) per (a,b) group, direct per-thread x gather (VGPR ~24).
__device__ __forceinline__ void poly_eval1(const float* __restrict__ sP,
                                           const float (&xv)[9], float (&acc)[4]) {
    const float* p1 = sP;
    const float* p2 = sP + 9 * 4;
    const float* p3 = sP + 54 * 4;
    int i2 = 0, i3 = 0;
#pragma unroll
    for (int a = 0; a < 9; ++a) {
        float4 q1 = *(const float4*)(p1 + a * 4);
        float xa = xv[a];
        acc[0] = fmaf(q1.x, xa, acc[0]);
        acc[1] = fmaf(q1.y, xa, acc[1]);
        acc[2] = fmaf(q1.z, xa, acc[2]);
        acc[3] = fmaf(q1.w, xa, acc[3]);
        __builtin_amdgcn_sched_barrier(0);
#pragma unroll
        for (int b = a; b < 9; ++b) {
            float4 q2 = *(const float4*)(p2 + i2 * 4);
            ++i2;
            float m2 = xv[a] * xv[b];
            acc[0] = fmaf(q2.x, m2, acc[0]);
            acc[1] = fmaf(q2.y, m2, acc[1]);
            acc[2] = fmaf(q2.z, m2, acc[2]);
            acc[3] = fmaf(q2.w, m2, acc[3]);
#pragma unroll
            for (int i = b; i < 9; ++i) {
                float4 q3 = *(const float4*)(p3 + i3 * 4);
                ++i3;
                float m3 = m2 * xv[i];
                acc[0] = fmaf(q3.x, m3, acc[0]);
                acc[1] = fmaf(q3.y, m3, acc[1]);
                acc[2] = fmaf(q3.z, m3, acc[2]);
                acc[3] = fmaf(q3.w, m3, acc[3]);
            }
            __builtin_amdgcn_sched_barrier(0);
        }
    }
}

__global__ __launch_bounds__(256) void k_poly(
    const float* __restrict__ x, const int* __restrict__ jlist,
    const int* __restrict__ chE, const int* __restrict__ chJ,
    const int* __restrict__ chEnd, const float* __restrict__ P,
    float* __restrict__ bout) {
    int ci = blockIdx.y;
    int e = chE[ci];
    if (e < 0) return;
    e = __builtin_amdgcn_readfirstlane(e);
    int c = blockIdx.x;
    const float* __restrict__ Pg = P + (size_t)(e * C_CH + c) * PSTRIDE;

    const int end = chEnd[ci];
    const int j = chJ[ci] + threadIdx.x;
    if (j >= end) return;
    const int n = jlist[j];
    if (n < 0) return;

    float xv[9];
    const float* px = x + ((size_t)n * C_CH + c) * 9;
#pragma unroll
    for (int i = 0; i < 9; ++i) xv[i] = px[i];
    float acc[4] = {};
    poly_eval1(Pg, xv, acc);
#pragma unroll
    for (int m = 0; m < 4; ++m) bout[(size_t)(c * 4 + m) * NP + j] = acc[m];
}

// j-lane GEMM v6: 2 d-groups/block (16 d/thread) — halves the redundant
// bout re-read (38.8 -> 19.4 MB) while keeping 592 blocks (~2.3/CU, 9
// waves/CU; R8-v4's 296-block collapse was the occupancy trap). W rows:
// 16 consecutive floats per t at a wave-uniform readfirstlane address ->
// scalar loads, no R9-v4 dwordx16x16 SGPR burst. Live ~58 VGPR (bv[32] +
// acc[16] + addr) — under the 64-reg/8-wave RA target.
__global__ __launch_bounds__(256) void k_linear(
    const float* __restrict__ bout, const int* __restrict__ jlist,
    const float* __restrict__ Wl0, const float* __restrict__ Wl1,
    const float* __restrict__ sc, float* __restrict__ out) {
    const int s  = blockIdx.y >> 1;                 // slot 0..3
    const int dh = blockIdx.y & 1;                  // d-half 0..1
    const int jj = threadIdx.x & 63;
    const int wv = threadIdx.x >> 6;                // 0..3
    const int dbase = __builtin_amdgcn_readfirstlane(dh * 64 + wv * 16);
    const int j = blockIdx.x * 64 + jj;
    const float* __restrict__ Wl = (s == 0) ? Wl0 : Wl1;
    const float* __restrict__ brow = bout + (size_t)s * NP + j;

    float acc[16];
#pragma unroll
    for (int k = 0; k < 16; ++k) acc[k] = 0.f;

#pragma unroll 1
    for (int cc0 = 0; cc0 < C_CH; cc0 += 32) {
        float bv[32];
#pragma unroll
        for (int t = 0; t < 32; ++t)
            bv[t] = brow[(size_t)(cc0 + t) * 4 * NP];
#pragma unroll
        for (int t = 0; t < 32; ++t) {
            const float* wrow = Wl + (cc0 + t) * C_CH + dbase;  // scalar addr
#pragma unroll
            for (int k = 0; k < 16; ++k) acc[k] = fmaf(bv[t], wrow[k], acc[k]);
        }
    }

    const int n = jlist[j];
    if (n < 0) return;
    const float inv = 0.08838834764831845f;  // 1/sqrt(128)
#pragma unroll
    for (int k = 0; k < 16; ++k) {
        int d = dbase + k;
        int col = (s == 0) ? d : (128 + d * 3 + (s - 1));
        out[n * 512 + col] = fmaf(acc[k], inv, sc[n * 512 + col]);
    }
}

extern "C" void kernel_launch(void* const* d_in, const int* in_sizes, int n_in,
                              void* d_out, int out_size, void* d_ws, size_t ws_size,
                              hipStream_t stream) {
    const float* x     = (const float*)d_in[0];
    const float* sc    = (const float*)d_in[1];
    const float* attrs = (const float*)d_in[2];
    const float* U3_0 = (const float*)d_in[3];
    const float* U2_0 = (const float*)d_in[4];
    const float* U1_0 = (const float*)d_in[5];
    const float* W3_0 = (const float*)d_in[6];
    const float* W2_0 = (const float*)d_in[7];
    const float* W1_0 = (const float*)d_in[8];
    const float* Wl0  = (const float*)d_in[9];
    const float* U3_1 = (const float*)d_in[10];
    const float* U2_1 = (const float*)d_in[11];
    const float* U1_1 = (const float*)d_in[12];
    const float* W3_1 = (const float*)d_in[13];
    const float* W2_1 = (const float*)d_in[14];
    const float* W1_1 = (const float*)d_in[15];
    const float* Wl1  = (const float*)d_in[16];

    char* ws = (char*)d_ws;
    int* chE     = (int*)(ws + WS_CHE);
    int* chJ     = (int*)(ws + WS_CHJ);
    int* chEnd   = (int*)(ws + WS_CHEND);
    int* jlist   = (int*)(ws + WS_JLIST);
    int* elem    = (int*)(ws + WS_ELEM);
    int* bcnt    = (int*)(ws + WS_BCNT);
    float* S31   = (float*)(ws + WS_S31);
    float* S30   = (float*)(ws + WS_S30);
    float* S21   = (float*)(ws + WS_S21);
    float* S20   = (float*)(ws + WS_S20);
    float* P     = (float*)(ws + WS_P);
    float* bout  = (float*)(ws + WS_BOUT);

    // L1: sym + elem decode + per-block counts
    k_front<<<35, 256, 0, stream>>>(attrs, elem, bcnt, U3_1, U3_0, U2_1, U2_0,
                                    S31, S30, S21, S20);
    // L2: parallel scatter (0-15) || table+pads (16) || fold P (17+)
    k_sortfold<<<NB + 1 + 1280, 256, 0, stream>>>(
        elem, bcnt, jlist, chE, chJ, chEnd,
        S31, S30, S21, S20, U1_1, U1_0,
        W3_1, W3_0, W2_1, W2_0, W1_1, W1_0, P);
    // L3: 219-monomial cubic (s_load coefficients + barriers, direct gather)
    k_poly<<<dim3(128, MAXCHUNK), 256, 0, stream>>>(x, jlist, chE, chJ, chEnd,
                                                    P, bout);
    // L4: channel-mixing linear + residual (2 d-groups/block)
    k_linear<<<dim3(NP / 64, 8), 256, 0, stream>>>(bout, jlist, Wl0, Wl1, sc,
                                                   (float*)d_out);
}

// Round 21
// 77.341 us; speedup vs baseline: 1.1839x; 1.1839x over previous
//
#include <hip/hip_runtime.h>

#define N_NODES 4096
#define C_CH    128
#define E_ELEM  10
#define NP      4736          // padded sorted-node space (64-aligned per element)
#define NB      16            // decode/scatter blocks (256 nodes each)
#define TT      219           // 9 deg1 + 45 deg2 + 165 deg3 monomials
#define PSTRIDE (TT * 4)      // 876 floats per (e,c): [t][m], m0=L0, m1..3=L1
#define MAXCHUNK 32
#define CHUNK_J  256          // j-slots per k_poly block (256 thr x 1 node)

// ws layout (bytes):
#define WS_CHE     256
#define WS_CHJ     512
#define WS_CHEND   768
#define WS_JLIST   1024        // int[4736]
#define WS_ELEM    20480       // int[4096]
#define WS_BCNT    36864       // int[160] per-block element counts
#define WS_S31     53248       // float[3465]
#define WS_S30     67136       // float[825]
#define WS_S21     70464       // float[405]
#define WS_S20     72128       // float[90]
#define WS_P       72704       // float[1280*876] = 4485120 B
#define WS_BOUT    4557824     // float[512*4736] = 9699328 B

// NOTE (R18): hipLaunchCooperativeKernel + grid.sync() DEADLOCKS under the
// harness's graph capture. Plain stream launches only.
// NOTE (R20): k_linear's (74,16)/8-d/bv[32] shape is a sharp local optimum —
// 296-block (R8), 592-block (R20), SGPR-burst (R9) variants all lose 30+ us.

__device__ __forceinline__ void t3_decode(int t, int& a, int& b, int& i) {
    int cnt = 0;
    for (int aa = 0; aa < 9; ++aa)
        for (int bb = aa; bb < 9; ++bb) {
            int len = 9 - bb;
            if (t < cnt + len) { a = aa; b = bb; i = bb + (t - cnt); return; }
            cnt += len;
        }
    a = b = i = 8;
}

__device__ __forceinline__ void t2_decode(int t, int& a, int& b) {
    int cnt = 0;
    for (int aa = 0; aa < 9; ++aa) {
        int len = 9 - aa;
        if (t < cnt + len) { a = aa; b = aa + (t - cnt); return; }
        cnt += len;
    }
    a = b = 8;
}

// Front: blocks 0-18 symmetrize U; blocks 19-34 decode elem AND produce
// per-block element counts bcnt[b][e].
__global__ __launch_bounds__(256) void k_front(
    const float* __restrict__ attrs, int* __restrict__ elem,
    int* __restrict__ bcnt,
    const float* __restrict__ U3_1, const float* __restrict__ U3_0,
    const float* __restrict__ U2_1, const float* __restrict__ U2_0,
    float* __restrict__ S31, float* __restrict__ S30,
    float* __restrict__ S21, float* __restrict__ S20) {
    int bid = blockIdx.x;
    int tid = threadIdx.x;
    if (bid >= 19) {
        __shared__ int h[E_ELEM];
        if (tid < E_ELEM) h[tid] = 0;
        __syncthreads();
        int b = bid - 19;
        int n = b * 256 + tid;                      // 16*256 = 4096 exact
        const float* a = attrs + n * E_ELEM;
        float best = a[0];
        int e = 0;
#pragma unroll
        for (int k = 1; k < E_ELEM; ++k) {
            float v = a[k];
            if (v > best) { best = v; e = k; }
        }
        elem[n] = e;
        atomicAdd(&h[e], 1);
        __syncthreads();
        if (tid < E_ELEM) bcnt[b * E_ELEM + tid] = h[tid];
        return;
    }
    int q = bid * 256 + tid;
    if (q < 3465) {                                 // S31 [m][t][p], p=7
        int m = q / 1155, r = q % 1155, t = r / 7, p = r % 7;
        int a, b, i;
        t3_decode(t, a, b, i);
#define U31(X, Y, Z) U3_1[((((m * 9 + (X)) * 9 + (Y)) * 9 + (Z)) * 7) + p]
        float s = U31(a, b, i);
        if (a == b && b == i) {}
        else if (a == b) s += U31(a, i, a) + U31(i, a, a);
        else if (b == i) s += U31(b, a, b) + U31(b, b, a);
        else s += U31(a, i, b) + U31(b, a, i) + U31(b, i, a) + U31(i, a, b) + U31(i, b, a);
#undef U31
        S31[q] = s;
        return;
    }
    q -= 3465;
    if (q < 825) {                                  // S30 [t][p], p=5
        int t = q / 5, p = q % 5;
        int a, b, i;
        t3_decode(t, a, b, i);
#define U30(X, Y, Z) U3_0[((((X) * 9 + (Y)) * 9 + (Z)) * 5) + p]
        float s = U30(a, b, i);
        if (a == b && b == i) {}
        else if (a == b) s += U30(a, i, a) + U30(i, a, a);
        else if (b == i) s += U30(b, a, b) + U30(b, b, a);
        else s += U30(a, i, b) + U30(b, a, i) + U30(b, i, a) + U30(i, a, b) + U30(i, b, a);
#undef U30
        S30[q] = s;
        return;
    }
    q -= 825;
    if (q < 405) {                                  // S21 [m][t][p], p=3
        int m = q / 135, r = q % 135, t = r / 3, p = r % 3;
        int a, b;
        t2_decode(t, a, b);
        float s = U2_1[(((m * 9 + a) * 9 + b) * 3) + p];
        if (a != b) s += U2_1[(((m * 9 + b) * 9 + a) * 3) + p];
        S21[q] = s;
        return;
    }
    q -= 405;
    if (q < 90) {                                   // S20 [t][p], p=2
        int t = q / 2, p = q % 2;
        int a, b;
        t2_decode(t, a, b);
        float s = U2_0[((a * 9 + b) * 2) + p];
        if (a != b) s += U2_0[((b * 9 + a) * 2) + p];
        S20[q] = s;
    }
}

// Redundant 160-int scan: every block computes the padded prefix itself.
__device__ __forceinline__ void scan_bcnt(const int* __restrict__ bcnt,
                                          int tid, int (&s_bc)[NB * E_ELEM],
                                          int (&s_cnt)[E_ELEM], int (&s_ps)[E_ELEM + 1]) {
    if (tid < NB * E_ELEM) s_bc[tid] = bcnt[tid];
    __syncthreads();
    if (tid < E_ELEM) {
        int c = 0;
#pragma unroll
        for (int b = 0; b < NB; ++b) c += s_bc[b * E_ELEM + tid];
        s_cnt[tid] = c;
    }
    __syncthreads();
    if (tid == 0) {
        int s = 0;
        for (int e = 0; e < E_ELEM; ++e) {
            s_ps[e] = s;
            s += ((s_cnt[e] + 63) >> 6) << 6;       // 64-align each range
        }
        s_ps[E_ELEM] = s;
    }
    __syncthreads();
}

// Sort+table+fold, all parallel (proven R15 shape).
__global__ __launch_bounds__(256) void k_sortfold(
    const int* __restrict__ elem, const int* __restrict__ bcnt,
    int* __restrict__ jlist,
    int* __restrict__ chE, int* __restrict__ chJ, int* __restrict__ chEnd,
    const float* __restrict__ S31, const float* __restrict__ S30,
    const float* __restrict__ S21, const float* __restrict__ S20,
    const float* __restrict__ U1_1, const float* __restrict__ U1_0,
    const float* __restrict__ W3_1, const float* __restrict__ W3_0,
    const float* __restrict__ W2_1, const float* __restrict__ W2_0,
    const float* __restrict__ W1_1, const float* __restrict__ W1_0,
    float* __restrict__ P) {
    const int bid = blockIdx.x;
    const int tid = threadIdx.x;
    if (bid < NB) {                                 // scatter blocks
        __shared__ int s_bc[NB * E_ELEM];
        __shared__ int s_cnt[E_ELEM];
        __shared__ int s_ps[E_ELEM + 1];
        __shared__ int cur[E_ELEM];
        scan_bcnt(bcnt, tid, s_bc, s_cnt, s_ps);
        if (tid < E_ELEM) {
            int off = s_ps[tid];
            for (int b = 0; b < bid; ++b) off += s_bc[b * E_ELEM + tid];
            cur[tid] = off;
        }
        __syncthreads();
        int n = bid * 256 + tid;
        int e = elem[n];
        int pos = atomicAdd(&cur[e], 1);
        jlist[pos] = n;
        return;
    }
    if (bid == NB) {                                // table + pad fill
        __shared__ int s_bc[NB * E_ELEM];
        __shared__ int s_cnt[E_ELEM];
        __shared__ int s_ps[E_ELEM + 1];
        scan_bcnt(bcnt, tid, s_bc, s_cnt, s_ps);
        if (tid == 0) {
            int ci = 0;
            for (int e = 0; e < E_ELEM; ++e) {
                int base = s_ps[e], pend = s_ps[e + 1];
                int end = base + s_cnt[e];
                for (int ofs = base; ofs < pend; ofs += CHUNK_J) {
                    chE[ci] = e;
                    chJ[ci] = ofs;
                    chEnd[ci] = end;
                    ++ci;
                }
            }
            for (; ci < MAXCHUNK; ++ci) chE[ci] = -1;
        }
        for (int j = tid; j < NP; j += 256) {
            bool pad = j >= s_ps[E_ELEM];
            if (!pad) {
#pragma unroll
                for (int e = 0; e < E_ELEM; ++e)
                    if (j >= s_ps[e] && j < s_ps[e + 1] && j >= s_ps[e] + s_cnt[e])
                        pad = true;
            }
            if (pad) jlist[j] = -1;
        }
        return;
    }
    // fold blocks: (e,c) = bid - 17
    int fb = bid - NB - 1;
    int e = fb >> 7;
    int c = fb & 127;
    float* Pout = P + (size_t)fb * PSTRIDE;
    for (int q = tid; q < PSTRIDE; q += 256) {
        int t = q >> 2, m = q & 3;
        float v;
        if (t < 9) {
            int a = t;
            v = (m == 0) ? U1_0[a] * W1_0[e * C_CH + c]
                         : U1_1[(m - 1) * 9 + a] * W1_1[e * C_CH + c];
        } else if (t < 54) {
            int t2 = t - 9;
            float s = 0.f;
            if (m == 0) {
#pragma unroll
                for (int p = 0; p < 2; ++p)
                    s = fmaf(S20[t2 * 2 + p], W2_0[(e * 2 + p) * C_CH + c], s);
            } else {
#pragma unroll
                for (int p = 0; p < 3; ++p)
                    s = fmaf(S21[((m - 1) * 45 + t2) * 3 + p], W2_1[(e * 3 + p) * C_CH + c], s);
            }
            v = s;
        } else {
            int t3 = t - 54;
            float s = 0.f;
            if (m == 0) {
#pragma unroll
                for (int p = 0; p < 5; ++p)
                    s = fmaf(S30[t3 * 5 + p], W3_0[(e * 5 + p) * C_CH + c], s);
            } else {
#pragma unroll
                for (int p = 0; p < 7; ++p)
                    s = fmaf(S31[((m - 1) * 165 + t3) * 7 + p], W3_1[(e * 7 + p) * C_CH + c], s);
            }
            v = s;
        }
        Pout[q] = v;
    }
}

// 219-monomial cubic — proven body: s_load coefficients, NN=1,
// sched_barrier(0) per (a,b) group, direct per-thread x gather (VGPR ~24).
__device__ __forceinline__ void poly_eval1(const float* __restrict__ sP,
                                           const float (&xv)[9], float (&acc)[4]) {
    const float* p1 = sP;
    const float* p2 = sP + 9 * 4;
    const float* p3 = sP + 54 * 4;
    int i2 = 0, i3 = 0;
#pragma unroll
    for (int a = 0; a < 9; ++a) {
        float4 q1 = *(const float4*)(p1 + a * 4);
        float xa = xv[a];
        acc[0] = fmaf(q1.x, xa, acc[0]);
        acc[1] = fmaf(q1.y, xa, acc[1]);
        acc[2] = fmaf(q1.z, xa, acc[2]);
        acc[3] = fmaf(q1.w, xa, acc[3]);
        __builtin_amdgcn_sched_barrier(0);
#pragma unroll
        for (int b = a; b < 9; ++b) {
            float4 q2 = *(const float4*)(p2 + i2 * 4);
            ++i2;
            float m2 = xv[a] * xv[b];
            acc[0] = fmaf(q2.x, m2, acc[0]);
            acc[1] = fmaf(q2.y, m2, acc[1]);
            acc[2] = fmaf(q2.z, m2, acc[2]);
            acc[3] = fmaf(q2.w, m2, acc[3]);
#pragma unroll
            for (int i = b; i < 9; ++i) {
                float4 q3 = *(const float4*)(p3 + i3 * 4);
                ++i3;
                float m3 = m2 * xv[i];
                acc[0] = fmaf(q3.x, m3, acc[0]);
                acc[1] = fmaf(q3.y, m3, acc[1]);
                acc[2] = fmaf(q3.z, m3, acc[2]);
                acc[3] = fmaf(q3.w, m3, acc[3]);
            }
            __builtin_amdgcn_sched_barrier(0);
        }
    }
}

__global__ __launch_bounds__(256) void k_poly(
    const float* __restrict__ x, const int* __restrict__ jlist,
    const int* __restrict__ chE, const int* __restrict__ chJ,
    const int* __restrict__ chEnd, const float* __restrict__ P,
    float* __restrict__ bout) {
    int ci = blockIdx.y;
    int e = chE[ci];
    if (e < 0) return;
    e = __builtin_amdgcn_readfirstlane(e);
    int c = blockIdx.x;
    const float* __restrict__ Pg = P + (size_t)(e * C_CH + c) * PSTRIDE;

    const int end = chEnd[ci];
    const int j = chJ[ci] + threadIdx.x;
    if (j >= end) return;
    const int n = jlist[j];
    if (n < 0) return;

    float xv[9];
    const float* px = x + ((size_t)n * C_CH + c) * 9;
#pragma unroll
    for (int i = 0; i < 9; ++i) xv[i] = px[i];
    float acc[4] = {};
    poly_eval1(Pg, xv, acc);
#pragma unroll
    for (int m = 0; m < 4; ++m) bout[(size_t)(c * 4 + m) * NP + j] = acc[m];
}

// j-lane GEMM (proven R10/R17 shape — do not perturb): grid (74,16), D=8
// d/thread via wave-uniform readfirstlane (s_load W), bv batched 32-deep.
__global__ __launch_bounds__(256) void k_linear(
    const float* __restrict__ bout, const int* __restrict__ jlist,
    const float* __restrict__ Wl0, const float* __restrict__ Wl1,
    const float* __restrict__ sc, float* __restrict__ out) {
    const int s  = blockIdx.y >> 2;
    const int dg = blockIdx.y & 3;
    const int jj = threadIdx.x & 63;
    const int wv = threadIdx.x >> 6;
    const int dbase = __builtin_amdgcn_readfirstlane(dg * 32 + wv * 8);
    const int j = blockIdx.x * 64 + jj;
    const float* __restrict__ Wl = (s == 0) ? Wl0 : Wl1;
    const float* __restrict__ brow = bout + (size_t)s * NP + j;

    float acc[8];
#pragma unroll
    for (int k = 0; k < 8; ++k) acc[k] = 0.f;

#pragma unroll 1
    for (int cc0 = 0; cc0 < C_CH; cc0 += 32) {
        float bv[32];
#pragma unroll
        for (int t = 0; t < 32; ++t)
            bv[t] = brow[(size_t)(cc0 + t) * 4 * NP];
#pragma unroll
        for (int t = 0; t < 32; ++t) {
            const float* wrow = Wl + (cc0 + t) * C_CH + dbase;  // scalar addr
#pragma unroll
            for (int k = 0; k < 8; ++k) acc[k] = fmaf(bv[t], wrow[k], acc[k]);
        }
    }

    const int n = jlist[j];
    if (n < 0) return;
    const float inv = 0.08838834764831845f;  // 1/sqrt(128)
#pragma unroll
    for (int k = 0; k < 8; ++k) {
        int d = dbase + k;
        int col = (s == 0) ? d : (128 + d * 3 + (s - 1));
        out[n * 512 + col] = fmaf(acc[k], inv, sc[n * 512 + col]);
    }
}

extern "C" void kernel_launch(void* const* d_in, const int* in_sizes, int n_in,
                              void* d_out, int out_size, void* d_ws, size_t ws_size,
                              hipStream_t stream) {
    const float* x     = (const float*)d_in[0];
    const float* sc    = (const float*)d_in[1];
    const float* attrs = (const float*)d_in[2];
    const float* U3_0 = (const float*)d_in[3];
    const float* U2_0 = (const float*)d_in[4];
    const float* U1_0 = (const float*)d_in[5];
    const float* W3_0 = (const float*)d_in[6];
    const float* W2_0 = (const float*)d_in[7];
    const float* W1_0 = (const float*)d_in[8];
    const float* Wl0  = (const float*)d_in[9];
    const float* U3_1 = (const float*)d_in[10];
    const float* U2_1 = (const float*)d_in[11];
    const float* U1_1 = (const float*)d_in[12];
    const float* W3_1 = (const float*)d_in[13];
    const float* W2_1 = (const float*)d_in[14];
    const float* W1_1 = (const float*)d_in[15];
    const float* Wl1  = (const float*)d_in[16];

    char* ws = (char*)d_ws;
    int* chE     = (int*)(ws + WS_CHE);
    int* chJ     = (int*)(ws + WS_CHJ);
    int* chEnd   = (int*)(ws + WS_CHEND);
    int* jlist   = (int*)(ws + WS_JLIST);
    int* elem    = (int*)(ws + WS_ELEM);
    int* bcnt    = (int*)(ws + WS_BCNT);
    float* S31   = (float*)(ws + WS_S31);
    float* S30   = (float*)(ws + WS_S30);
    float* S21   = (float*)(ws + WS_S21);
    float* S20   = (float*)(ws + WS_S20);
    float* P     = (float*)(ws + WS_P);
    float* bout  = (float*)(ws + WS_BOUT);

    // L1: sym + elem decode + per-block counts
    k_front<<<35, 256, 0, stream>>>(attrs, elem, bcnt, U3_1, U3_0, U2_1, U2_0,
                                    S31, S30, S21, S20);
    // L2: parallel scatter (0-15) || table+pads (16) || fold P (17+)
    k_sortfold<<<NB + 1 + 1280, 256, 0, stream>>>(
        elem, bcnt, jlist, chE, chJ, chEnd,
        S31, S30, S21, S20, U1_1, U1_0,
        W3_1, W3_0, W2_1, W2_0, W1_1, W1_0, P);
    // L3: 219-monomial cubic (s_load coefficients + barriers, direct gather)
    k_poly<<<dim3(128, MAXCHUNK), 256, 0, stream>>>(x, jlist, chE, chJ, chEnd,
                                                    P, bout);
    // L4: channel-mixing linear + residual
    k_linear<<<dim3(NP / 64, 16), 256, 0, stream>>>(bout, jlist, Wl0, Wl1, sc,
                                                    (float*)d_out);
}